// Round 5
// baseline (77.402 us; speedup 1.0000x reference)
//
#include <hip/hip_runtime.h>
#include <hip/hip_bf16.h>

#define L_ 30
#define NB 2
#define NN 64
#define NM 64
#define MCH 16

// ws float offsets
#define O_BOP  0        // 128
#define O_WEWK 128      // 4x128
#define O_CK   640      // 30x128
#define O_QS   4480     // 128x128 (q / sqrt(dh))
#define O_GT   20864    // ushort[128][168] transposed G (rows e, cols k)
#define O_CTR  32768    // unsigned ready-counter (memset to 0 each call)

typedef __attribute__((ext_vector_type(8))) short short8;
typedef __attribute__((ext_vector_type(4))) float f32x4;

__device__ __forceinline__ unsigned short f2b(float v) {
    union { float f; unsigned int u; } x; x.f = v;
    unsigned int u = x.u + 0x7FFFu + ((x.u >> 16) & 1u);
    return (unsigned short)(u >> 16);
}
__device__ __forceinline__ float b2f(unsigned short s) {
    union { unsigned int u; float f; } x; x.u = ((unsigned int)s) << 16; return x.f;
}
__device__ __forceinline__ float dot4(float4 a, float4 b) {
    return a.x*b.x + a.y*b.y + a.z*b.z + a.w*b.w;
}

// 640 blocks: 0..127 = pre (one output column e each), 128..639 = main.
// Handoff: pre blocks release-signal ctr; main blocks RMW-spin (device scope).
// Co-residency guaranteed: launch_bounds(256,3) => >=3 blocks/CU = 768 slots >= 640.
__global__ __launch_bounds__(256, 3)
void k_all(const float* __restrict__ agent, const float* __restrict__ lane,
           const float* __restrict__ We,  const float* __restrict__ be,
           const float* __restrict__ Wa,  const float* __restrict__ ba,
           const float* __restrict__ pe,
           const float* __restrict__ Wq,  const float* __restrict__ bq,
           const float* __restrict__ Wk,  const float* __restrict__ bk,
           const float* __restrict__ Wv,  const float* __restrict__ bv,
           const float* __restrict__ Wo,  const float* __restrict__ bo,
           const float* __restrict__ Wp,  const float* __restrict__ bp,
           float* __restrict__ ws, float* __restrict__ out) {

    __shared__ __align__(16) char smem[21824];   // overlay: pre 20.1KB | main 21.8KB
    const int t = threadIdx.x;
    const int bid = blockIdx.x;
    unsigned* ctr = (unsigned*)(ws + O_CTR);

    if (bid < 128) {
        // ---------------- PRE: one output column e ----------------
        const int e = bid;
        float* pb     = (float*)smem;
        float* wp_s   = pb;           // 128
        float* wq_s   = pb + 128;     // 128
        float* wk_s   = pb + 256;     // 128
        float* wop_s  = pb + 384;     // 128
        float* wawq_s = pb + 512;     // 12
        float* misc   = pb + 524;     // [0]=bqq [1..4]=dbv
        float* pesum  = pb + 532;     // 30*132
        float* wvop   = pb + 4492;    // 4*132

        if (t < 128) { wp_s[t] = Wp[t*128+e]; wq_s[t] = Wq[t*128+e]; }
        else         { int d = t-128; wk_s[d] = Wk[d*128+e]; }
        for (int i = t; i < 30*128; i += 256) {
            int l = i >> 7, d = i & 127;
            pesum[l*132+d] = be[d] + pe[l*128+d];
        }
        __syncthreads();

        if (t < 128) {
            const float4* wo  = (const float4*)(Wo + t*128);
            const float4* wp4 = (const float4*)wp_s;
            float a = 0.f;
            #pragma unroll 8
            for (int i = 0; i < 32; ++i) a += dot4(wo[i], wp4[i]);
            wop_s[t] = a;
        } else if (t < 158) {
            int l = t - 128;
            const float4* pl  = (const float4*)(pesum + l*132);
            const float4* wk4 = (const float4*)wk_s;
            float a = bk[e];
            #pragma unroll 8
            for (int i = 0; i < 32; ++i) a += dot4(pl[i], wk4[i]);
            ws[O_CK + l*128 + e] = a;
        } else if (t < 170) {
            int f = t - 158;
            const float4* wa4 = (const float4*)(Wa + f*128);
            const float4* wq4 = (const float4*)wq_s;
            float a = 0.f;
            #pragma unroll 8
            for (int i = 0; i < 32; ++i) a += dot4(wa4[i], wq4[i]);
            wawq_s[f] = a;
        } else if (t == 170) {
            float a = bq[e];
            for (int d = 0; d < 128; ++d) a += ba[d]*wq_s[d];
            misc[0] = a;
        } else if (t >= 172 && t < 176) {
            int j = t - 172;
            const float4* wej = (const float4*)(We + j*128);
            const float4* wk4 = (const float4*)wk_s;
            float a = 0.f;
            #pragma unroll 8
            for (int i = 0; i < 32; ++i) a += dot4(wej[i], wk4[i]);
            ws[O_WEWK + j*128 + e] = a;
        }
        __syncthreads();

        #pragma unroll
        for (int kk = 0; kk < 2; ++kk) {
            int job = t*2 + kk;
            int h = job & 3, d = job >> 2;
            const float4* wv4 = (const float4*)(Wv + d*128 + h*32);
            const float4* wc4 = (const float4*)(wop_s + h*32);
            float a = 0.f;
            #pragma unroll
            for (int i = 0; i < 8; ++i) a += dot4(wv4[i], wc4[i]);
            wvop[h*132 + d] = a;
        }
        if (t < 128) {
            float a = misc[0];
            const float* ag = agent + t*16;
            a += ag[2]*wawq_s[0];
            #pragma unroll
            for (int f = 1; f < 12; ++f) a += ag[4+f]*wawq_s[f];
            ws[O_QS + t*128 + e] = a * 0.17677669529663687f;
        } else if (t < 132) {
            int h = t-128;
            float a = 0.f;
            for (int c = 0; c < 32; ++c) a += bv[h*32+c]*wop_s[h*32+c];
            misc[1+h] = a;
        } else if (t == 132) {
            float a = bp[e];
            for (int c = 0; c < 128; ++c) a += bo[c]*wop_s[c];
            ws[O_BOP + e] = a;
        }
        __syncthreads();

        unsigned short* GT = (unsigned short*)(ws + O_GT);
        if (t < 16) {
            int h = t >> 2, j = t & 3;
            const float4* wej = (const float4*)(We + j*128);
            const float4* wv4 = (const float4*)(wvop + h*132);
            float a = 0.f;
            #pragma unroll 8
            for (int i = 0; i < 32; ++i) a += dot4(wej[i], wv4[i]);
            GT[e*168 + t] = f2b(a);
        } else if (t < 136) {
            int r = t-16; int h = r/30, l = r - h*30;
            const float4* pl  = (const float4*)(pesum + l*132);
            const float4* wv4 = (const float4*)(wvop + h*132);
            float a = misc[1+h];
            #pragma unroll 8
            for (int i = 0; i < 32; ++i) a += dot4(pl[i], wv4[i]);
            GT[e*168 + t] = f2b(a);
        } else if (t < 168) {
            GT[e*168 + t] = 0;
        }

        // release: all writes visible device-wide, then count up
        __syncthreads();
        __threadfence();
        if (t == 0) atomicAdd(ctr, 1u);
        return;
    }

    // ---------------- MAIN ----------------
    const int bid2 = bid - 128;
    const int bn = bid2 >> 2;
    const int m0 = (bid2 & 3) * MCH;
    const int b = bn >> 6;

    float (*ScE)[124] = (float (*)[124])smem;                         // edges f32 [m][l*4+k]
    float (*ScS)[124] = (float (*)[124])(smem + 7936);                // scores [m][h*30+l]
    unsigned short (*WcB)[168] = (unsigned short (*)[168])(smem + 15872);
    float* u_s = (float*)(smem + 21248);                              // 16
    float* c_s = (float*)(smem + 21312);                              // 120

    // prefix (independent of pre): WcB tail zero + edge geometry
    for (int i = t; i < 16*24; i += 256) {
        int m = i / 24;
        WcB[m][136 + (i - m*24)] = 0;
    }
    const float ax  = agent[bn*16+0], ay = agent[bn*16+1];
    const float as_ = agent[bn*16+3], ac = agent[bn*16+4];
    const float f1 = (ax==0.f && ay==0.f && as_==0.f && ac==0.f) ? 0.f : 1.f;
    for (int job = t; job < MCH*30; job += 256) {
        int m = job / 30, l = job - m*30;
        const float* lp = lane + (size_t)((b*NM + m0 + m)*L_ + l)*4;
        float4 lv = *(const float4*)lp;
        float f2 = (lv.x==0.f && lv.y==0.f && lv.z==0.f && lv.w==0.f) ? 0.f : 1.f;
        float f = f1 * f2;
        float dx = lv.x - ax, dy = lv.y - ay;
        ScE[m][l*4+0] = (ac*dx + as_*dy) * 0.1f * f;
        ScE[m][l*4+1] = (ac*dy - as_*dx) * 0.1f * f;
        ScE[m][l*4+2] = (lv.z*ac - lv.w*as_) * f;
        ScE[m][l*4+3] = (lv.w*ac + lv.z*as_) * f;
    }

    // acquire: wait for all 128 pre blocks (RMW spin reaches device-coherent point)
    if (t == 0) {
        while (atomicAdd(ctr, 0u) < 128u) { __builtin_amdgcn_s_sleep(8); }
    }
    __syncthreads();
    __threadfence();

    // prefetch G fragments + bias to registers (hide L2/L3 latency under M0..M3)
    const unsigned short* GT = (const unsigned short*)(ws + O_GT);
    const int lane_id = t & 63;
    const int wv = t >> 6;
    const int frm = lane_id & 15;
    const int kg  = lane_id >> 4;
    const int e0 = wv*32 + frm;
    short8 g0[5], g1[5];
    #pragma unroll
    for (int i = 0; i < 5; ++i) {
        g0[i] = *(const short8*)&GT[(size_t)e0*168 + i*32 + kg*8];
        g1[i] = *(const short8*)&GT[(size_t)(e0+16)*168 + i*32 + kg*8];
    }
    const float bb0 = ws[O_BOP + e0];
    const float bb1 = ws[O_BOP + e0 + 16];

    // M0: per-agent u (4x4) and c (4x30)
    if (t < 136) {
        if (t < 16) {
            int h = t >> 2, j = t & 3;
            const float4* x = (const float4*)(ws + O_WEWK + j*128 + h*32);
            const float4* y = (const float4*)(ws + O_QS + bn*128 + h*32);
            float a = 0.f;
            #pragma unroll
            for (int i = 0; i < 8; ++i) a += dot4(x[i], y[i]);
            u_s[t] = a;
        } else {
            int r = t - 16; int h = r/30, l = r - h*30;
            const float4* x = (const float4*)(ws + O_CK + l*128 + h*32);
            const float4* y = (const float4*)(ws + O_QS + bn*128 + h*32);
            float a = 0.f;
            #pragma unroll
            for (int i = 0; i < 8; ++i) a += dot4(x[i], y[i]);
            c_s[r] = a;
        }
    }
    __syncthreads();

    // M1: scores from stored edges
    for (int job = t; job < MCH*30; job += 256) {
        int m = job / 30, l = job - m*30;
        float rx = ScE[m][l*4+0], ry = ScE[m][l*4+1];
        float rs = ScE[m][l*4+2], rc = ScE[m][l*4+3];
        #pragma unroll
        for (int h = 0; h < 4; ++h) {
            ScS[m][h*30 + l] = rx*u_s[h*4+0] + ry*u_s[h*4+1] + rs*u_s[h*4+2]
                             + rc*u_s[h*4+3] + c_s[h*30+l];
        }
    }
    __syncthreads();

    // M2: softmax, 4 lanes per (m,h), static 8-slot unroll (no scratch)
    {
        const int m = t >> 4, hh = (t >> 2) & 3, s = t & 3;
        float vals[8];
        float mx = -1e30f;
        #pragma unroll
        for (int k = 0; k < 8; ++k) {
            int l = s + 4*k;
            vals[k] = (l < 30) ? ScS[m][hh*30 + l] : -1e30f;
            mx = fmaxf(mx, vals[k]);
        }
        mx = fmaxf(mx, __shfl_xor(mx, 1, 64));
        mx = fmaxf(mx, __shfl_xor(mx, 2, 64));
        float sum = 0.f;
        #pragma unroll
        for (int k = 0; k < 8; ++k) {
            float ev = __expf(vals[k] - mx);
            ev = (s + 4*k < 30) ? ev : 0.f;
            vals[k] = ev; sum += ev;
        }
        sum += __shfl_xor(sum, 1, 64);
        sum += __shfl_xor(sum, 2, 64);
        float inv = 1.f / sum;
        #pragma unroll
        for (int k = 0; k < 8; ++k) {
            int l = s + 4*k;
            if (l < 30) WcB[m][16 + hh*30 + l] = f2b(vals[k]*inv);
        }
    }
    __syncthreads();

    // M3: we4 -> bf16 into WcB[m][h*4+j]
    {
        int m = t >> 4, i = t & 15;
        int hh = i >> 2, j = i & 3;
        float a = 0.f;
        for (int l = 0; l < 30; ++l)
            a += b2f(WcB[m][16 + hh*30 + l]) * ScE[m][l*4 + j];
        WcB[m][i] = f2b(a);
    }
    __syncthreads();

    // M4: OUT[16x128] = WcB[16x160] @ G[160x128] via MFMA (B from regs)
    {
        f32x4 acc0 = {bb0, bb0, bb0, bb0};
        f32x4 acc1 = {bb1, bb1, bb1, bb1};
        #pragma unroll
        for (int i = 0; i < 5; ++i) {
            short8 a = *(const short8*)&WcB[frm][i*32 + kg*8];
            acc0 = __builtin_amdgcn_mfma_f32_16x16x32_bf16(a, g0[i], acc0, 0, 0, 0);
            acc1 = __builtin_amdgcn_mfma_f32_16x16x32_bf16(a, g1[i], acc1, 0, 0, 0);
        }
        float* ob = out + ((size_t)(bn*NM + m0))*128;
        #pragma unroll
        for (int r = 0; r < 4; ++r) {
            int m = kg*4 + r;
            ob[m*128 + e0]      = acc0[r];
            ob[m*128 + e0 + 16] = acc1[r];
        }
    }
}

extern "C" void kernel_launch(void* const* d_in, const int* in_sizes, int n_in,
                              void* d_out, int out_size, void* d_ws, size_t ws_size,
                              hipStream_t stream) {
    const float* agent = (const float*)d_in[0];
    const float* lane  = (const float*)d_in[1];
    const float* We = (const float*)d_in[2];
    const float* be = (const float*)d_in[3];
    const float* Wa = (const float*)d_in[4];
    const float* ba = (const float*)d_in[5];
    const float* pe = (const float*)d_in[6];
    const float* Wq = (const float*)d_in[7];
    const float* bq = (const float*)d_in[8];
    const float* Wk = (const float*)d_in[9];
    const float* bk = (const float*)d_in[10];
    const float* Wv = (const float*)d_in[11];
    const float* bv = (const float*)d_in[12];
    const float* Wo = (const float*)d_in[13];
    const float* bo = (const float*)d_in[14];
    const float* Wp = (const float*)d_in[15];
    const float* bp = (const float*)d_in[16];
    float* ws  = (float*)d_ws;
    float* out = (float*)d_out;

    hipMemsetAsync((char*)d_ws + O_CTR*sizeof(float), 0, sizeof(unsigned), stream);
    hipLaunchKernelGGL(k_all, dim3(128 + NB*NN*4), dim3(256), 0, stream,
                       agent, lane, We, be, Wa, ba, pe, Wq, bq, Wk, bk, Wv, bv,
                       Wo, bo, Wp, bp, ws, out);
}